// Round 6
// baseline (384.504 us; speedup 1.0000x reference)
//
#include <hip/hip_runtime.h>
#include <math.h>

// Workspace layout (4-byte words):
#define W2OFF  0        // 8192 floats: W2[e][d] = sum_o key[e][o]*Wq[o][d]
#define B2OFF  8192     // 8 floats:    b2[e]    = sum_d bq[d]*key[e][d]
#define SCOFF  8200     // 512 floats:  score sums [batch][e]
#define AUXOFF 8712     // 1 float:     sum of w*log(w+1e-9)   (== SCOFF+512)
#define ZTOT   513      // words to zero starting at SCOFF

// ---------------- k01: W2 = key@Wq, b2 = bq.key, zero accumulators ----------------
__global__ __launch_bounds__(256) void k01_prep(const float* __restrict__ Wq,
                                                const float* __restrict__ key,
                                                const float* __restrict__ bq,
                                                float* __restrict__ ws) {
    __shared__ __attribute__((aligned(16))) float keyl[8 * 1024];  // 32 KB
    __shared__ float part[256 * 8];                                // 8 KB
    __shared__ float part2[64];
    int tid = threadIdx.x;
    int blk = blockIdx.x;

    // distributed zeroing: 64 blocks x 9 words covers 513
    if (tid < 9) {
        int i = blk * 9 + tid;
        if (i < ZTOT) ws[SCOFF + i] = 0.0f;
    }

    float4* kl4 = (float4*)keyl;
    const float4* kg4 = (const float4*)key;
    #pragma unroll
    for (int k = 0; k < 8; ++k) kl4[tid + 256 * k] = kg4[tid + 256 * k];
    __syncthreads();

    // W2 slice: block owns 16 output columns d; 16 o-groups of 64.
    int dl = tid & 15;
    int og = tid >> 4;
    int d  = blk * 16 + dl;
    float acc[8];
    #pragma unroll
    for (int e = 0; e < 8; ++e) acc[e] = 0.0f;
    for (int oo = 0; oo < 64; ++oo) {
        int o = og * 64 + oo;
        float wv = Wq[o * 1024 + d];
        #pragma unroll
        for (int e = 0; e < 8; ++e) acc[e] += keyl[e * 1024 + o] * wv;
    }
    #pragma unroll
    for (int e = 0; e < 8; ++e) part[tid * 8 + e] = acc[e];
    __syncthreads();
    if (tid < 128) {
        int dl2 = tid >> 3, e = tid & 7;
        float s = 0.0f;
        #pragma unroll
        for (int g = 0; g < 16; ++g) s += part[(g * 16 + dl2) * 8 + e];
        ws[W2OFF + e * 1024 + blk * 16 + dl2] = s;
    }

    // block 0 additionally computes b2 using the LDS-staged key (tree reduce)
    if (blk == 0) {
        __syncthreads();
        float p[8];
        #pragma unroll
        for (int e = 0; e < 8; ++e) p[e] = 0.0f;
        #pragma unroll
        for (int k = 0; k < 4; ++k) {
            int d2 = tid + 256 * k;
            float bv = bq[d2];
            #pragma unroll
            for (int e = 0; e < 8; ++e) p[e] += bv * keyl[e * 1024 + d2];
        }
        #pragma unroll
        for (int e = 0; e < 8; ++e) part[tid * 8 + e] = p[e];
        __syncthreads();
        if (tid < 64) {                 // stage 1: 64 threads sum 32 rows each
            int e = tid & 7, g = tid >> 3;
            float s = 0.0f;
            #pragma unroll
            for (int k = 0; k < 32; ++k) s += part[(g * 32 + k) * 8 + e];
            part2[g * 8 + e] = s;
        }
        __syncthreads();
        if (tid < 8) {                  // stage 2: 8 threads sum 8 partials
            float s = 0.0f;
            #pragma unroll
            for (int g = 0; g < 8; ++g) s += part2[g * 8 + tid];
            ws[B2OFF + tid] = s;
        }
    }
}

// 8-value -> 1-value shfl fold over 64 lanes. Returns full 64-lane sum of
// v[cmap] where cmap = bitrev3(lane&7) = ((lane&1)<<2)|(lane&2)|((lane>>2)&1).
// Masks 1/2/4 fold the value dimension (quad-perm class, VALU-cheap);
// masks 8/16/32 butterfly the remaining single value.
__device__ __forceinline__ float fold_reduce8(const float v[8], int lane) {
    float t[4];
    bool h1 = (lane & 1) != 0;
    #pragma unroll
    for (int k = 0; k < 4; ++k) {
        float send = h1 ? v[k] : v[k + 4];
        float recv = __shfl_xor(send, 1);
        float keep = h1 ? v[k + 4] : v[k];
        t[k] = keep + recv;
    }
    float u[2];
    bool h2 = (lane & 2) != 0;
    #pragma unroll
    for (int k = 0; k < 2; ++k) {
        float send = h2 ? t[k] : t[k + 2];
        float recv = __shfl_xor(send, 2);
        float keep = h2 ? t[k + 2] : t[k];
        u[k] = keep + recv;
    }
    bool h4 = (lane & 4) != 0;
    float send = h4 ? u[0] : u[1];
    float recv = __shfl_xor(send, 4);
    float keep = h4 ? u[1] : u[0];
    float s = keep + recv;
    s += __shfl_xor(s, 8);
    s += __shfl_xor(s, 16);
    s += __shfl_xor(s, 32);
    return s;
}

// ---------------- k2: stream x -> raw scores -> phase-B softmax + sums ----------------
// 1024 blocks x 256 thr; block = 64 consecutive tokens of one batch.
// In-loop reduction is pure shfl fold (no LDS transpose) -> LDS = 34.8 KB
// -> 4 blocks/CU, all 1024 blocks co-resident (no dispatch tail).
// NOTE: no min-waves launch_bounds arg (R2: forcing it spilled acc to scratch).
__global__ __launch_bounds__(256) void k2_main(const float* __restrict__ x,
                                               float* __restrict__ ws) {
    __shared__ __attribute__((aligned(16))) float w2l[8 * 1024];  // 32 KB
    __shared__ __attribute__((aligned(16))) float sraw[64 * 8];   // 2 KB raw scores

    int tid  = threadIdx.x;
    int blk  = blockIdx.x;
    int lane = tid & 63;
    int w    = tid >> 6;
    int batch = blk >> 4;
    int tb    = blk * 64;
    int cmap = ((lane & 1) << 2) | (lane & 2) | ((lane >> 2) & 1);  // bitrev3(lane&7)

    float4* wl4 = (float4*)w2l;
    const float4* wg4 = (const float4*)(ws + W2OFF);
    #pragma unroll
    for (int k = 0; k < 8; ++k) wl4[tid + 256 * k] = wg4[tid + 256 * k];
    __syncthreads();

    const float4* x4 = (const float4*)x;

    for (int p = 0; p < 4; ++p) {
        int lt0 = w * 16 + p * 4;
        int t0  = tb + lt0;
        float acc[4][8];
        #pragma unroll
        for (int j = 0; j < 4; ++j)
            #pragma unroll
            for (int c = 0; c < 8; ++c) acc[j][c] = 0.0f;

        #pragma unroll
        for (int i = 0; i < 4; ++i) {
            float4 xr[4];
            #pragma unroll
            for (int j = 0; j < 4; ++j)
                xr[j] = x4[(size_t)(t0 + j) * 256 + i * 64 + lane];
            #pragma unroll
            for (int c = 0; c < 8; ++c) {
                float4 w4 = wl4[c * 256 + i * 64 + lane];
                #pragma unroll
                for (int j = 0; j < 4; ++j)
                    acc[j][c] += w4.x * xr[j].x + w4.y * xr[j].y +
                                 w4.z * xr[j].z + w4.w * xr[j].w;
            }
        }

        #pragma unroll
        for (int j = 0; j < 4; ++j) {
            float s = fold_reduce8(acc[j], lane);
            if (lane < 8) sraw[(lt0 + j) * 8 + cmap] = s;  // raw dot, pre-bias/scale
        }
    }
    __syncthreads();

    // Phase B: 64 threads, one token each, lane-local softmax
    if (tid < 64) {
        int t = tid;
        float sv[8];
        #pragma unroll
        for (int k = 0; k < 8; ++k) {        // rotated reads to spread banks
            int c = (t + k) & 7;
            sv[c] = sraw[t * 8 + c];
        }
        const float scale = 0.03125f;        // 1024^-0.5
        #pragma unroll
        for (int c = 0; c < 8; ++c) sv[c] = (sv[c] + ws[B2OFF + c]) * scale;
        float mx = sv[0];
        #pragma unroll
        for (int c = 1; c < 8; ++c) mx = fmaxf(mx, sv[c]);
        float wgt[8], sm = 0.0f;
        #pragma unroll
        for (int c = 0; c < 8; ++c) { wgt[c] = expf(sv[c] - mx); sm += wgt[c]; }
        float inv = 1.0f / sm;
        float aux = 0.0f;
        #pragma unroll
        for (int c = 0; c < 8; ++c) {
            wgt[c] *= inv;
            aux += wgt[c] * logf(wgt[c] + 1e-9f);
        }
        // block score-sum reduce: same fold trick (these 64 threads are wave 0)
        float s2 = fold_reduce8(wgt, t);
        if (t < 8) atomicAdd(&ws[SCOFF + batch * 8 + cmap], s2);
        #pragma unroll
        for (int mk = 1; mk <= 32; mk <<= 1) aux += __shfl_xor(aux, mk);
        if (t == 0) atomicAdd(&ws[AUXOFF], aux);
    }
}

// ---------------- k3: top-2, mask broadcast, indices, loss ----------------
__device__ __forceinline__ void top2_of8(const float* v, int& i1, int& i2) {
    i1 = 0; float b1 = v[0];
    #pragma unroll
    for (int e = 1; e < 8; ++e) if (v[e] > b1) { b1 = v[e]; i1 = e; }
    i2 = -1; float b2 = -3.4e38f;
    #pragma unroll
    for (int e = 0; e < 8; ++e) if (e != i1 && v[e] > b2) { b2 = v[e]; i2 = e; }
}

__global__ __launch_bounds__(256) void k3_out(const float* __restrict__ ws,
                                              float* __restrict__ out) {
    int tid = threadIdx.x;
    int blk = blockIdx.x;            // 256 blocks; 4 per batch
    int batch = blk >> 2;

    float v[8];
    #pragma unroll
    for (int e = 0; e < 8; ++e) v[e] = ws[SCOFF + batch * 8 + e];
    int i1, i2;
    top2_of8(v, i1, i2);

    float m[8];
    #pragma unroll
    for (int e = 0; e < 8; ++e) m[e] = (e == i1 || e == i2) ? 1.0f : 0.0f;
    int token = blk * 256 + tid;
    float4* o4 = (float4*)out;
    o4[token * 2]     = make_float4(m[0], m[1], m[2], m[3]);
    o4[token * 2 + 1] = make_float4(m[4], m[5], m[6], m[7]);

    if (blk == 0) {
        __shared__ int cnt[8];
        if (tid < 8) cnt[tid] = 0;
        __syncthreads();
        if (tid < 64) {
            float vv[8];
            #pragma unroll
            for (int e = 0; e < 8; ++e) vv[e] = ws[SCOFF + tid * 8 + e];
            int j1, j2;
            top2_of8(vv, j1, j2);
            out[524288 + tid * 2]     = (float)j1;
            out[524288 + tid * 2 + 1] = (float)j2;
            atomicAdd(&cnt[j1], 1);
            atomicAdd(&cnt[j2], 1);
        }
        __syncthreads();
        if (tid == 0) {
            float kl = 0.0f;
            #pragma unroll
            for (int e = 0; e < 8; ++e) {
                float usage = (float)cnt[e] / 64.0f;
                kl += 0.125f * (logf(0.125f) - logf(usage));
            }
            kl *= 0.125f;  // / E (batchmean)
            float aux = ws[AUXOFF] / 524288.0f;
            out[524416] = 1e-3f * kl + 1e-3f * aux;
        }
    }
}

extern "C" void kernel_launch(void* const* d_in, const int* in_sizes, int n_in,
                              void* d_out, int out_size, void* d_ws, size_t ws_size,
                              hipStream_t stream) {
    const float* x   = (const float*)d_in[0];
    const float* Wq  = (const float*)d_in[1];
    const float* bq  = (const float*)d_in[2];
    const float* key = (const float*)d_in[3];
    float* out = (float*)d_out;
    float* ws  = (float*)d_ws;

    k01_prep<<<64,   256, 0, stream>>>(Wq, key, bq, ws);
    k2_main<<<1024, 256, 0, stream>>>(x, ws);
    k3_out <<<256,  256, 0, stream>>>(ws, out);
}